// Round 10
// baseline (252.751 us; speedup 1.0000x reference)
//
#include <hip/hip_runtime.h>
#include <hip/hip_bf16.h>

#define BATCH 4
#define SEQ   2048
#define DM    1024
#define NH    16
#define DK    64
#define BH    (BATCH*NH)   // 64

typedef __attribute__((ext_vector_type(8))) short  bv8;   // 8 bf16 (4 VGPRs) MFMA frag
typedef __attribute__((ext_vector_type(4))) short  sv4;   // 4 bf16 (8B)
typedef __attribute__((ext_vector_type(4))) float  f32x4;

__device__ __forceinline__ short f2b(float f) {
    unsigned u = __builtin_bit_cast(unsigned, f);
    u += 0x7fffu + ((u >> 16) & 1u);          // RNE
    return (short)(u >> 16);
}
// packed f32x2 -> bf16x2 (RNE) via the COMPILER-NATIVE conversion (r8: works,
// attn off critical path). __hip_bfloat162 not trivially copyable -> memcpy.
__device__ __forceinline__ unsigned pk2(float lo, float hi) {
    float2 f; f.x = lo; f.y = hi;
    __hip_bfloat162 h = __float22bfloat162_rn(f);
    unsigned r;
    __builtin_memcpy(&r, &h, 4);
    return r;
}
__device__ __forceinline__ float b2f(short s) {
    unsigned u = ((unsigned)(unsigned short)s) << 16;
    return __builtin_bit_cast(float, u);
}

// async global->LDS, 16B per lane; LDS dest = wave-uniform base + lane*16;
// global source is PER-LANE — lanes must cover whole cache lines.
__device__ __forceinline__ void load_lds16(const short* g, short* l) {
    __builtin_amdgcn_global_load_lds(
        (const __attribute__((address_space(1))) void*)g,
        (__attribute__((address_space(3))) void*)l, 16, 0, 0);
}

// ---------------------------------------------------------------------------
// fp32 -> bf16 pre-convert. Flat grid of exactly 6144 blocks:
// [0,4096) -> x ; [4096,6144) -> Wq,Wk,Wv,Wo (512 each). No empty blocks.
// ---------------------------------------------------------------------------
__global__ __launch_bounds__(256) void cvt_kernel(
    const float* __restrict__ x,
    const float* __restrict__ wq, const float* __restrict__ wk,
    const float* __restrict__ wv, const float* __restrict__ wo,
    short* __restrict__ Xb, short* __restrict__ Wb)
{
    const int f = blockIdx.x;
    const float* src; short* dst; int idx0;
    if (f < 4096) { src = x; dst = Xb; idx0 = f; }
    else {
        int z   = (f - 4096) >> 9;     // 0..3
        int rel = (f - 4096) & 511;
        src = (z == 0) ? wq : (z == 1) ? wk : (z == 2) ? wv : wo;
        dst = Wb + (size_t)z * (DM * DM);
        idx0 = rel;
    }
    int idx = idx0 * 256 + threadIdx.x;            // 8-elem chunk
    const float4* s4 = (const float4*)src + (size_t)idx * 2;
    float4 a = s4[0], b = s4[1];
    union { unsigned u[4]; bv8 v; } o;
    o.u[0] = pk2(a.x, a.y);  o.u[1] = pk2(a.z, a.w);
    o.u[2] = pk2(b.x, b.y);  o.u[3] = pk2(b.z, b.w);
    *(bv8*)(dst + (size_t)idx * 8) = o.v;
}

// ---------------------------------------------------------------------------
// GEMM (NT, all-bf16).
//  (a) XCD-chunked block remap (proven r6: FETCH 200->49MB, 90->71us).
//  (b) bz==2 (V): V^T = Wv * X^T via operand swap -> s-contiguous stores.
//  (c) RoPE fused into the Q/K epilogue (r9, net -7us).
//  (d) NEW r10: trig recurrence. r9 spent 192 trans ops/thread (fract/sin/cos
//      per output). Now: per-nt hoist of invrev/sgn + unit-rotation (cw,sw);
//      one fract/sin/cos per (mt,nt) base row; rows r=1..3 via 2D rotation
//      (4 FMA each). 192 -> ~60 trans; fp32 rotation error ~1e-7 << bf16 ulp.
// ---------------------------------------------------------------------------
template<bool FINAL>
__global__ __launch_bounds__(256) void gemm_nt(
    const short* __restrict__ A, const short* __restrict__ Wall,
    short* __restrict__ Oq, short* __restrict__ Ok, short* __restrict__ Ov,
    float* __restrict__ FO)
{
    constexpr int K = 1024;
    __shared__ __align__(16) short As[128 * 64];   // 16 KB, slot16(r,c8)=r*8+(c8^(r&7))
    __shared__ __align__(16) short Ws[128 * 64];

    // (a) XCD-chunked remap
    const int flat  = (int)blockIdx.x + 8 * (int)blockIdx.y + 512 * (int)blockIdx.z;
    const int chunk = (512 * (int)gridDim.z) >> 3;
    const int L  = (flat & 7) * chunk + (flat >> 3);
    const int bn = L & 7, bm = (L >> 3) & 63, bz = L >> 9;

    // (b) operand roles
    const short* Ap; const short* Wp; int row0, col0;
    if (!FINAL && bz == 2) {
        Ap = Wall + 2 * (size_t)(DM * DM);   // Wv rows -> output rows (h*64+d)
        Wp = A;                              // X rows  -> output cols (b*2048+s)
        row0 = bn * 128; col0 = bm * 128;
    } else {
        Ap = A;
        Wp = Wall + (size_t)bz * (DM * DM);
        row0 = bm * 128; col0 = bn * 128;
    }

    const int tid = threadIdx.x;
    const int wave = tid >> 6, lane = tid & 63, lm = lane & 15, lq = lane >> 4;
    const int wr = wave >> 1, wc = wave & 1;

    f32x4 acc[4][4];
    for (int i = 0; i < 4; i++)
        for (int j = 0; j < 4; j++)
            acc[i][j] = f32x4{0.f, 0.f, 0.f, 0.f};

    const int rI = lane >> 3;              // row within instruction (0..7)
    const int cS = (lane & 7) ^ rI;        // swizzled 16B chunk (0..7)
    const short* gA[4]; const short* gW[4];
    short* lA[4]; short* lW[4];
    for (int j = 0; j < 4; j++) {
        int rl = wave * 32 + j * 8;
        gA[j] = Ap + (size_t)(row0 + rl + rI) * K + cS * 8;
        gW[j] = Wp + (size_t)(col0 + rl + rI) * K + cS * 8;
        lA[j] = &As[rl * 64];
        lW[j] = &Ws[rl * 64];
    }

    for (int kk = 0; kk < K; kk += 64) {
        for (int j = 0; j < 4; j++) {
            load_lds16(gA[j], lA[j]);  gA[j] += 64;
            load_lds16(gW[j], lW[j]);  gW[j] += 64;
        }
        __syncthreads();

        for (int h = 0; h < 2; h++) {
            bv8 af[4], bf[4];
            for (int mt = 0; mt < 4; mt++) {
                int r = wr * 64 + mt * 16 + lm;
                af[mt] = *(const bv8*)&As[r * 64 + (((h * 4 + lq) ^ (lm & 7)) * 8)];
            }
            for (int nt = 0; nt < 4; nt++) {
                int r = wc * 64 + nt * 16 + lm;
                bf[nt] = *(const bv8*)&Ws[r * 64 + (((h * 4 + lq) ^ (lm & 7)) * 8)];
            }
            for (int mt = 0; mt < 4; mt++)
                for (int nt = 0; nt < 4; nt++)
                    acc[mt][nt] = __builtin_amdgcn_mfma_f32_16x16x32_bf16(af[mt], bf[nt], acc[mt][nt], 0, 0, 0);
        }
        __syncthreads();
    }

    if constexpr (FINAL) {
        for (int mt = 0; mt < 4; mt++) {
            int mbase = row0 + wr * 64 + mt * 16 + lq * 4;
            for (int nt = 0; nt < 4; nt++) {
                int n = col0 + wc * 64 + nt * 16 + lm;
                for (int r = 0; r < 4; r++)
                    FO[(size_t)(mbase + r) * DM + n] = acc[mt][nt][r];
            }
        }
    } else if (bz == 2) {
        for (int mt = 0; mt < 4; mt++) {
            int mbase = row0 + wr * 64 + mt * 16 + lq * 4;
            for (int nt = 0; nt < 4; nt++) {
                int n = col0 + wc * 64 + nt * 16 + lm;
                for (int r = 0; r < 4; r++) {
                    int row = mbase + r;
                    int hh = row >> 6, d = row & 63;
                    int b = n >> 11, s = n & 2047;
                    Ov[((size_t)((b * NH + hh) * DK + d)) * SEQ + s] = f2b(acc[mt][nt][r]);
                }
            }
        }
    } else {
        // (c)+(d) fused RoPE for Q/K with trig recurrence; nt-outer to hoist
        // the d-dependent constants (d is fixed per (nt,lane)).
        const float scale = (bz == 0) ? 0.125f * 1.44269504089f : 1.0f;
        short* dst = (bz == 0) ? Oq : Ok;
        for (int nt = 0; nt < 4; nt++) {
            int n = col0 + wc * 64 + nt * 16 + lm;
            int h = n >> 6, d = n & 63;
            float invrev = __builtin_amdgcn_exp2f((float)(d >> 1) * -0.41522499f)
                           * 0.15915494309f;
            float sgn = (d & 1) ? 1.0f : -1.0f;
            float swr = __builtin_amdgcn_sinf(invrev);   // unit-s rotation
            float cwr = __builtin_amdgcn_cosf(invrev);
            for (int mt = 0; mt < 4; mt++) {
                int mbase = row0 + wr * 64 + mt * 16 + lq * 4;
                int b = mbase >> 11, s0 = mbase & 2047;  // no wrap within r<4
                float rev = __builtin_amdgcn_fractf((float)s0 * invrev);
                float sn = __builtin_amdgcn_sinf(rev);
                float cs = __builtin_amdgcn_cosf(rev);
                size_t obase = ((size_t)((b * NH + h) * SEQ + s0)) * DK + d;
                for (int r = 0; r < 4; r++) {
                    float v  = acc[mt][nt][r];
                    float pv = __shfl_xor(v, 1, 64);     // partner d^1, same row
                    float out = (v * cs + sgn * (pv * sn)) * scale;
                    dst[obase + (size_t)r * DK] = f2b(out);
                    float sn2 = sn * cwr + cs * swr;     // rotate to s0+r+1
                    float cs2 = cs * cwr - sn * swr;
                    sn = sn2; cs = cs2;
                }
            }
        }
    }
}

// ---------------------------------------------------------------------------
// Flash attention v11 = v10 + s_setprio(1) around the QK^T and PV MFMA
// clusters (T5: +4-7% on attn structures with wave role-diversity, m191;
// null only on lockstep GEMM). grid (S/256, BH), 256 thr = 4 waves; balanced
// q-tile pairs (15-x, x): 34 tile-steps per block, phase-aligned streams per
// XCD (no remap — r4 showed co-locating phase-skewed streams doubles time).
// ---------------------------------------------------------------------------
__global__ __launch_bounds__(256, 4) void attn_kernel(
    const short* __restrict__ Qb, const short* __restrict__ Kb,
    const short* __restrict__ Vb, short* __restrict__ Cb)
{
    __shared__ __align__(16) short Ks[2][4096];   // [buf][key*64 + swz] 8KB/buf
    __shared__ __align__(16) short Vs[2][4096];   // [buf][d*64 + swz]

    const int bx = (int)blockIdx.x;   // q-pair index
    const int bh = (int)blockIdx.y;   // head

    const int tid = threadIdx.x, wave = tid >> 6, lane = tid & 63;
    const int lm = lane & 15, lq = lane >> 4;
    const size_t base = (size_t)bh * SEQ * DK;

    const int sr = lane >> 3;
    const int sc = (lane & 7) ^ sr;
    const short* gK0 = Kb + base + (size_t)(wave * 16 + sr) * DK + sc * 8;
    const short* gK1 = Kb + base + (size_t)(wave * 16 + 8 + sr) * DK + sc * 8;
    const short* gV0 = Vb + base + (size_t)(wave * 16 + sr) * SEQ + sc * 8;
    const short* gV1 = Vb + base + (size_t)(wave * 16 + 8 + sr) * SEQ + sc * 8;
    short* lK0[2] = { &Ks[0][(wave * 16) * 64],     &Ks[1][(wave * 16) * 64] };
    short* lK1[2] = { &Ks[0][(wave * 16 + 8) * 64], &Ks[1][(wave * 16 + 8) * 64] };
    short* lV0[2] = { &Vs[0][(wave * 16) * 64],     &Vs[1][(wave * 16) * 64] };
    short* lV1[2] = { &Vs[0][(wave * 16 + 8) * 64], &Vs[1][(wave * 16 + 8) * 64] };

    const int sw = lm & 7;
    const int bb = bh >> 4, hh = bh & 15;
    constexpr int NQT = SEQ / 128;                 // 16 q-tiles

    for (int pass = 0; pass < 2; ++pass) {
        // complementary pair: pass 0 -> heavy qt = 15-bx, pass 1 -> light qt = bx
        const int qt = pass ? bx : (NQT - 1 - bx);
        const int q0 = qt * 128;

        // Q frags (used as MFMA B-operand; same lane layout as A)
        bv8 aQ[2][2];
        for (int mg = 0; mg < 2; mg++) {
            const short* qp = Qb + base + (size_t)(q0 + wave * 32 + mg * 16 + lm) * DK + lq * 8;
            aQ[mg][0] = *(const bv8*)qp;
            aQ[mg][1] = *(const bv8*)(qp + 32);
        }

        f32x4 oacc[2][4];
        float rsum[2] = {0.f, 0.f};               // per-lane: one query (lm) per mg
        for (int mg = 0; mg < 2; mg++)
            for (int nt = 0; nt < 4; nt++) oacc[mg][nt] = f32x4{0.f, 0.f, 0.f, 0.f};

        const int last = 2 * qt + 1;
        const int qrow_base = q0 + wave * 32 + lm;    // + mg*16 -> this lane's query

        load_lds16(gK0, lK0[0]);  load_lds16(gK1, lK1[0]);
        load_lds16(gV0, lV0[0]);  load_lds16(gV1, lV1[0]);
        __syncthreads();

        for (int kt = 0; kt <= last; ++kt) {
            const int b = kt & 1;
            if (kt < last) {                           // prefetch overlaps compute
                const size_t ko = (size_t)(kt + 1) * 64 * DK;
                const size_t vo = (size_t)(kt + 1) * 64;
                load_lds16(gK0 + ko, lK0[b ^ 1]);  load_lds16(gK1 + ko, lK1[b ^ 1]);
                load_lds16(gV0 + vo, lV0[b ^ 1]);  load_lds16(gV1 + vo, lV1[b ^ 1]);
            }

            // S^T tiles: t[mg][nt] reg r = S[query mg*16+lm][key kt*64+nt*16+lq*4+r]
            // (already scaled by log2e via Q pre-scale)
            f32x4 t[2][4];
            __builtin_amdgcn_s_setprio(1);
            for (int nt = 0; nt < 4; nt++) {
                const short* kp = &Ks[b][(nt * 16 + lm) * 64];
                bv8 kf0 = *(const bv8*)(kp + ((lq ^ sw) * 8));
                bv8 kf1 = *(const bv8*)(kp + (((4 + lq) ^ sw) * 8));
                for (int mg = 0; mg < 2; mg++) {
                    f32x4 z = f32x4{0.f, 0.f, 0.f, 0.f};
                    z = __builtin_amdgcn_mfma_f32_16x16x32_bf16(kf0, aQ[mg][0], z, 0, 0, 0);
                    z = __builtin_amdgcn_mfma_f32_16x16x32_bf16(kf1, aQ[mg][1], z, 0, 0, 0);
                    t[mg][nt] = z;
                }
            }
            __builtin_amdgcn_s_setprio(0);

            // mask (diagonal region only) + exp2 + lane-local l-sum + lane-local
            // repack into PV A-frags (key order psi: j<4 -> tile 2h, j>=4 -> 2h+1)
            bv8 aP[2][2];
            for (int mg = 0; mg < 2; mg++) {
                const int qrow = qrow_base + mg * 16;
                if (kt >= 2 * qt) {
                    for (int nt = 0; nt < 4; nt++) {
                        int keyb = kt * 64 + nt * 16 + lq * 4;
                        for (int r = 0; r < 4; r++)
                            t[mg][nt][r] = (keyb + r <= qrow) ? t[mg][nt][r] : -1e30f;
                    }
                }
                for (int nt = 0; nt < 4; nt++)
                    for (int r = 0; r < 4; r++) {
                        float p = __builtin_amdgcn_exp2f(t[mg][nt][r]);
                        rsum[mg] += p;
                        t[mg][nt][r] = p;
                    }
                for (int h = 0; h < 2; h++) {
                    union { unsigned u[4]; bv8 v; } pk;
                    pk.u[0] = pk2(t[mg][2 * h][0],     t[mg][2 * h][1]);
                    pk.u[1] = pk2(t[mg][2 * h][2],     t[mg][2 * h][3]);
                    pk.u[2] = pk2(t[mg][2 * h + 1][0], t[mg][2 * h + 1][1]);
                    pk.u[3] = pk2(t[mg][2 * h + 1][2], t[mg][2 * h + 1][3]);
                    aP[mg][h] = pk.v;
                }
            }

            // O += P V with the psi key order: B-frag element j on lane (lq,lm) =
            // V[32h + (j>>2)*16 + lq*4 + (j&3)][d = nt*16+lm] -> two 8B reads.
            __builtin_amdgcn_s_setprio(1);
            for (int nt = 0; nt < 4; nt++) {
                const short* vrow = &Vs[b][(nt * 16 + lm) * 64];
                for (int h = 0; h < 2; h++) {
                    int c8 = h * 4 + (lq >> 1);
                    union { sv4 q[2]; bv8 v; } vv;
                    vv.q[0] = *(const sv4*)(vrow + ((c8 ^ sw) * 8)       + (lq & 1) * 4);
                    vv.q[1] = *(const sv4*)(vrow + (((c8 ^ 2) ^ sw) * 8) + (lq & 1) * 4);
                    for (int mg = 0; mg < 2; mg++)
                        oacc[mg][nt] = __builtin_amdgcn_mfma_f32_16x16x32_bf16(aP[mg][h], vv.v, oacc[mg][nt], 0, 0, 0);
                }
            }
            __builtin_amdgcn_s_setprio(0);
            __syncthreads();   // releases buf b for the next prefetch
        }

        // l-sum: add the 4 lq quadrants (each lane then has full sum for query lm)
        for (int mg = 0; mg < 2; mg++) {
            rsum[mg] += __shfl_xor(rsum[mg], 16, 64);
            rsum[mg] += __shfl_xor(rsum[mg], 32, 64);
        }

        // epilogue: oacc rows are queries lq*4+r; fetch that query's l from lane lq*4+r
        for (int mg = 0; mg < 2; mg++)
            for (int r = 0; r < 4; r++) {
                float l = __shfl(rsum[mg], lq * 4 + r, 64);
                float inv = 1.0f / l;
                int srow = q0 + wave * 32 + mg * 16 + lq * 4 + r;
                size_t rowbase = ((size_t)(bb * SEQ + srow)) * DM + hh * DK;
                for (int nt = 0; nt < 4; nt++)
                    Cb[rowbase + nt * 16 + lm] = f2b(oacc[mg][nt][r] * inv);
            }
    }
}

// ---------------------------------------------------------------------------
extern "C" void kernel_launch(void* const* d_in, const int* in_sizes, int n_in,
                              void* d_out, int out_size, void* d_ws, size_t ws_size,
                              hipStream_t stream)
{
    const float* x  = (const float*)d_in[0];
    const float* Wq = (const float*)d_in[1];
    const float* Wk = (const float*)d_in[2];
    const float* Wv = (const float*)d_in[3];
    const float* Wo = (const float*)d_in[4];
    float* out = (float*)d_out;

    const size_t TSZ = (size_t)BH * SEQ * DK;   // 8,388,608 elems (16 MB bf16)
    short* Qb  = (short*)d_ws;
    short* Kb  = Qb + TSZ;
    short* Vb  = Kb + TSZ;
    short* XCb = Vb + TSZ;            // x-bf16 during proj; ctx after attention
    short* Wb  = XCb + TSZ;           // 4x [1024][1024] bf16 (Wq,Wk,Wv,Wo)

    // fp32 -> bf16 pre-convert (x + all four W), exact 6144-block grid
    cvt_kernel<<<dim3(6144), 256, 0, stream>>>(x, Wq, Wk, Wv, Wo, XCb, Wb);
    // QKV projection + fused RoPE (z: 0=Q scaled,1=K,2=V transposed)
    gemm_nt<false><<<dim3(8, 64, 3), 256, 0, stream>>>(
        XCb, Wb, Qb, Kb, Vb, nullptr);
    // causal flash attention -> ctx (aliases XCb)
    attn_kernel<<<dim3(SEQ / 256, BH), 256, 0, stream>>>(Qb, Kb, Vb, XCb);
    // output projection (fp32 out)
    gemm_nt<true><<<dim3(8, 64, 1), 256, 0, stream>>>(
        XCb, Wb + 3 * (size_t)(DM * DM), nullptr, nullptr, nullptr, out);
}

// Round 11
// 236.087 us; speedup vs baseline: 1.0706x; 1.0706x over previous
//
#include <hip/hip_runtime.h>
#include <hip/hip_bf16.h>

#define BATCH 4
#define SEQ   2048
#define DM    1024
#define NH    16
#define DK    64
#define BH    (BATCH*NH)   // 64

typedef __attribute__((ext_vector_type(8))) short  bv8;   // 8 bf16 (4 VGPRs) MFMA frag
typedef __attribute__((ext_vector_type(4))) short  sv4;   // 4 bf16 (8B)
typedef __attribute__((ext_vector_type(4))) float  f32x4;

__device__ __forceinline__ short f2b(float f) {
    unsigned u = __builtin_bit_cast(unsigned, f);
    u += 0x7fffu + ((u >> 16) & 1u);          // RNE
    return (short)(u >> 16);
}
// packed f32x2 -> bf16x2 (RNE) via the COMPILER-NATIVE conversion (r8: works,
// attn off critical path). __hip_bfloat162 not trivially copyable -> memcpy.
__device__ __forceinline__ unsigned pk2(float lo, float hi) {
    float2 f; f.x = lo; f.y = hi;
    __hip_bfloat162 h = __float22bfloat162_rn(f);
    unsigned r;
    __builtin_memcpy(&r, &h, 4);
    return r;
}
__device__ __forceinline__ float b2f(short s) {
    unsigned u = ((unsigned)(unsigned short)s) << 16;
    return __builtin_bit_cast(float, u);
}

// async global->LDS, 16B per lane; LDS dest = wave-uniform base + lane*16;
// global source is PER-LANE — lanes must cover whole cache lines.
__device__ __forceinline__ void load_lds16(const short* g, short* l) {
    __builtin_amdgcn_global_load_lds(
        (const __attribute__((address_space(1))) void*)g,
        (__attribute__((address_space(3))) void*)l, 16, 0, 0);
}

// ---------------------------------------------------------------------------
// fp32 -> bf16 pre-convert. Flat grid of exactly 6144 blocks:
// [0,4096) -> x ; [4096,6144) -> Wq,Wk,Wv,Wo (512 each). No empty blocks.
// ---------------------------------------------------------------------------
__global__ __launch_bounds__(256) void cvt_kernel(
    const float* __restrict__ x,
    const float* __restrict__ wq, const float* __restrict__ wk,
    const float* __restrict__ wv, const float* __restrict__ wo,
    short* __restrict__ Xb, short* __restrict__ Wb)
{
    const int f = blockIdx.x;
    const float* src; short* dst; int idx0;
    if (f < 4096) { src = x; dst = Xb; idx0 = f; }
    else {
        int z   = (f - 4096) >> 9;     // 0..3
        int rel = (f - 4096) & 511;
        src = (z == 0) ? wq : (z == 1) ? wk : (z == 2) ? wv : wo;
        dst = Wb + (size_t)z * (DM * DM);
        idx0 = rel;
    }
    int idx = idx0 * 256 + threadIdx.x;            // 8-elem chunk
    const float4* s4 = (const float4*)src + (size_t)idx * 2;
    float4 a = s4[0], b = s4[1];
    union { unsigned u[4]; bv8 v; } o;
    o.u[0] = pk2(a.x, a.y);  o.u[1] = pk2(a.z, a.w);
    o.u[2] = pk2(b.x, b.y);  o.u[3] = pk2(b.z, b.w);
    *(bv8*)(dst + (size_t)idx * 8) = o.v;
}

// ---------------------------------------------------------------------------
// GEMM (NT, all-bf16).
//  (a) XCD-chunked block remap (proven r6: FETCH 200->49MB, 90->71us).
//  (b) bz==2 (V): V^T = Wv * X^T via operand swap -> s-contiguous stores.
//  (c) RoPE fused into the Q/K epilogue (r9, net -7us).
//  (d) trig recurrence (r10): per-nt hoist + one fract/sin/cos per (mt,nt)
//      base row, rows r=1..3 via 2D rotation. 192 -> ~60 trans ops/thread.
// ---------------------------------------------------------------------------
template<bool FINAL>
__global__ __launch_bounds__(256) void gemm_nt(
    const short* __restrict__ A, const short* __restrict__ Wall,
    short* __restrict__ Oq, short* __restrict__ Ok, short* __restrict__ Ov,
    float* __restrict__ FO)
{
    constexpr int K = 1024;
    __shared__ __align__(16) short As[128 * 64];   // 16 KB, slot16(r,c8)=r*8+(c8^(r&7))
    __shared__ __align__(16) short Ws[128 * 64];

    // (a) XCD-chunked remap
    const int flat  = (int)blockIdx.x + 8 * (int)blockIdx.y + 512 * (int)blockIdx.z;
    const int chunk = (512 * (int)gridDim.z) >> 3;
    const int L  = (flat & 7) * chunk + (flat >> 3);
    const int bn = L & 7, bm = (L >> 3) & 63, bz = L >> 9;

    // (b) operand roles
    const short* Ap; const short* Wp; int row0, col0;
    if (!FINAL && bz == 2) {
        Ap = Wall + 2 * (size_t)(DM * DM);   // Wv rows -> output rows (h*64+d)
        Wp = A;                              // X rows  -> output cols (b*2048+s)
        row0 = bn * 128; col0 = bm * 128;
    } else {
        Ap = A;
        Wp = Wall + (size_t)bz * (DM * DM);
        row0 = bm * 128; col0 = bn * 128;
    }

    const int tid = threadIdx.x;
    const int wave = tid >> 6, lane = tid & 63, lm = lane & 15, lq = lane >> 4;
    const int wr = wave >> 1, wc = wave & 1;

    f32x4 acc[4][4];
    for (int i = 0; i < 4; i++)
        for (int j = 0; j < 4; j++)
            acc[i][j] = f32x4{0.f, 0.f, 0.f, 0.f};

    const int rI = lane >> 3;              // row within instruction (0..7)
    const int cS = (lane & 7) ^ rI;        // swizzled 16B chunk (0..7)
    const short* gA[4]; const short* gW[4];
    short* lA[4]; short* lW[4];
    for (int j = 0; j < 4; j++) {
        int rl = wave * 32 + j * 8;
        gA[j] = Ap + (size_t)(row0 + rl + rI) * K + cS * 8;
        gW[j] = Wp + (size_t)(col0 + rl + rI) * K + cS * 8;
        lA[j] = &As[rl * 64];
        lW[j] = &Ws[rl * 64];
    }

    for (int kk = 0; kk < K; kk += 64) {
        for (int j = 0; j < 4; j++) {
            load_lds16(gA[j], lA[j]);  gA[j] += 64;
            load_lds16(gW[j], lW[j]);  gW[j] += 64;
        }
        __syncthreads();

        for (int h = 0; h < 2; h++) {
            bv8 af[4], bf[4];
            for (int mt = 0; mt < 4; mt++) {
                int r = wr * 64 + mt * 16 + lm;
                af[mt] = *(const bv8*)&As[r * 64 + (((h * 4 + lq) ^ (lm & 7)) * 8)];
            }
            for (int nt = 0; nt < 4; nt++) {
                int r = wc * 64 + nt * 16 + lm;
                bf[nt] = *(const bv8*)&Ws[r * 64 + (((h * 4 + lq) ^ (lm & 7)) * 8)];
            }
            for (int mt = 0; mt < 4; mt++)
                for (int nt = 0; nt < 4; nt++)
                    acc[mt][nt] = __builtin_amdgcn_mfma_f32_16x16x32_bf16(af[mt], bf[nt], acc[mt][nt], 0, 0, 0);
        }
        __syncthreads();
    }

    if constexpr (FINAL) {
        for (int mt = 0; mt < 4; mt++) {
            int mbase = row0 + wr * 64 + mt * 16 + lq * 4;
            for (int nt = 0; nt < 4; nt++) {
                int n = col0 + wc * 64 + nt * 16 + lm;
                for (int r = 0; r < 4; r++)
                    FO[(size_t)(mbase + r) * DM + n] = acc[mt][nt][r];
            }
        }
    } else if (bz == 2) {
        for (int mt = 0; mt < 4; mt++) {
            int mbase = row0 + wr * 64 + mt * 16 + lq * 4;
            for (int nt = 0; nt < 4; nt++) {
                int n = col0 + wc * 64 + nt * 16 + lm;
                for (int r = 0; r < 4; r++) {
                    int row = mbase + r;
                    int hh = row >> 6, d = row & 63;
                    int b = n >> 11, s = n & 2047;
                    Ov[((size_t)((b * NH + hh) * DK + d)) * SEQ + s] = f2b(acc[mt][nt][r]);
                }
            }
        }
    } else {
        // (c)+(d) fused RoPE for Q/K with trig recurrence; nt-outer to hoist
        // the d-dependent constants (d is fixed per (nt,lane)).
        const float scale = (bz == 0) ? 0.125f * 1.44269504089f : 1.0f;
        short* dst = (bz == 0) ? Oq : Ok;
        for (int nt = 0; nt < 4; nt++) {
            int n = col0 + wc * 64 + nt * 16 + lm;
            int h = n >> 6, d = n & 63;
            float invrev = __builtin_amdgcn_exp2f((float)(d >> 1) * -0.41522499f)
                           * 0.15915494309f;
            float sgn = (d & 1) ? 1.0f : -1.0f;
            float swr = __builtin_amdgcn_sinf(invrev);   // unit-s rotation
            float cwr = __builtin_amdgcn_cosf(invrev);
            for (int mt = 0; mt < 4; mt++) {
                int mbase = row0 + wr * 64 + mt * 16 + lq * 4;
                int b = mbase >> 11, s0 = mbase & 2047;  // no wrap within r<4
                float rev = __builtin_amdgcn_fractf((float)s0 * invrev);
                float sn = __builtin_amdgcn_sinf(rev);
                float cs = __builtin_amdgcn_cosf(rev);
                size_t obase = ((size_t)((b * NH + h) * SEQ + s0)) * DK + d;
                for (int r = 0; r < 4; r++) {
                    float v  = acc[mt][nt][r];
                    float pv = __shfl_xor(v, 1, 64);     // partner d^1, same row
                    float out = (v * cs + sgn * (pv * sn)) * scale;
                    dst[obase + (size_t)r * DK] = f2b(out);
                    float sn2 = sn * cwr + cs * swr;     // rotate to s0+r+1
                    float cs2 = cs * cwr - sn * swr;
                    sn = sn2; cs = cs2;
                }
            }
        }
    }
}

// ---------------------------------------------------------------------------
// Flash attention v12 = v10 (r9 code), setprio REVERTED. r10's setprio
// regressed attn 70->80us: our 4 waves are barrier-locked per kt-step
// (__syncthreads each tile), which is the m190 lockstep-GEMM case where T5
// is null-to-negative — NOT m191's independent-phase attn. Priority boost +
// barrier = priority inversion against the co-resident block's prefetch.
// grid (S/256, BH), 256 thr = 4 waves; balanced q-tile pairs (15-x, x):
// 34 tile-steps per block, phase-aligned streams per XCD (no remap — r4).
// ---------------------------------------------------------------------------
__global__ __launch_bounds__(256, 4) void attn_kernel(
    const short* __restrict__ Qb, const short* __restrict__ Kb,
    const short* __restrict__ Vb, short* __restrict__ Cb)
{
    __shared__ __align__(16) short Ks[2][4096];   // [buf][key*64 + swz] 8KB/buf
    __shared__ __align__(16) short Vs[2][4096];   // [buf][d*64 + swz]

    const int bx = (int)blockIdx.x;   // q-pair index
    const int bh = (int)blockIdx.y;   // head

    const int tid = threadIdx.x, wave = tid >> 6, lane = tid & 63;
    const int lm = lane & 15, lq = lane >> 4;
    const size_t base = (size_t)bh * SEQ * DK;

    const int sr = lane >> 3;
    const int sc = (lane & 7) ^ sr;
    const short* gK0 = Kb + base + (size_t)(wave * 16 + sr) * DK + sc * 8;
    const short* gK1 = Kb + base + (size_t)(wave * 16 + 8 + sr) * DK + sc * 8;
    const short* gV0 = Vb + base + (size_t)(wave * 16 + sr) * SEQ + sc * 8;
    const short* gV1 = Vb + base + (size_t)(wave * 16 + 8 + sr) * SEQ + sc * 8;
    short* lK0[2] = { &Ks[0][(wave * 16) * 64],     &Ks[1][(wave * 16) * 64] };
    short* lK1[2] = { &Ks[0][(wave * 16 + 8) * 64], &Ks[1][(wave * 16 + 8) * 64] };
    short* lV0[2] = { &Vs[0][(wave * 16) * 64],     &Vs[1][(wave * 16) * 64] };
    short* lV1[2] = { &Vs[0][(wave * 16 + 8) * 64], &Vs[1][(wave * 16 + 8) * 64] };

    const int sw = lm & 7;
    const int bb = bh >> 4, hh = bh & 15;
    constexpr int NQT = SEQ / 128;                 // 16 q-tiles

    for (int pass = 0; pass < 2; ++pass) {
        // complementary pair: pass 0 -> heavy qt = 15-bx, pass 1 -> light qt = bx
        const int qt = pass ? bx : (NQT - 1 - bx);
        const int q0 = qt * 128;

        // Q frags (used as MFMA B-operand; same lane layout as A)
        bv8 aQ[2][2];
        for (int mg = 0; mg < 2; mg++) {
            const short* qp = Qb + base + (size_t)(q0 + wave * 32 + mg * 16 + lm) * DK + lq * 8;
            aQ[mg][0] = *(const bv8*)qp;
            aQ[mg][1] = *(const bv8*)(qp + 32);
        }

        f32x4 oacc[2][4];
        float rsum[2] = {0.f, 0.f};               // per-lane: one query (lm) per mg
        for (int mg = 0; mg < 2; mg++)
            for (int nt = 0; nt < 4; nt++) oacc[mg][nt] = f32x4{0.f, 0.f, 0.f, 0.f};

        const int last = 2 * qt + 1;
        const int qrow_base = q0 + wave * 32 + lm;    // + mg*16 -> this lane's query

        load_lds16(gK0, lK0[0]);  load_lds16(gK1, lK1[0]);
        load_lds16(gV0, lV0[0]);  load_lds16(gV1, lV1[0]);
        __syncthreads();

        for (int kt = 0; kt <= last; ++kt) {
            const int b = kt & 1;
            if (kt < last) {                           // prefetch overlaps compute
                const size_t ko = (size_t)(kt + 1) * 64 * DK;
                const size_t vo = (size_t)(kt + 1) * 64;
                load_lds16(gK0 + ko, lK0[b ^ 1]);  load_lds16(gK1 + ko, lK1[b ^ 1]);
                load_lds16(gV0 + vo, lV0[b ^ 1]);  load_lds16(gV1 + vo, lV1[b ^ 1]);
            }

            // S^T tiles: t[mg][nt] reg r = S[query mg*16+lm][key kt*64+nt*16+lq*4+r]
            // (already scaled by log2e via Q pre-scale)
            f32x4 t[2][4];
            for (int nt = 0; nt < 4; nt++) {
                const short* kp = &Ks[b][(nt * 16 + lm) * 64];
                bv8 kf0 = *(const bv8*)(kp + ((lq ^ sw) * 8));
                bv8 kf1 = *(const bv8*)(kp + (((4 + lq) ^ sw) * 8));
                for (int mg = 0; mg < 2; mg++) {
                    f32x4 z = f32x4{0.f, 0.f, 0.f, 0.f};
                    z = __builtin_amdgcn_mfma_f32_16x16x32_bf16(kf0, aQ[mg][0], z, 0, 0, 0);
                    z = __builtin_amdgcn_mfma_f32_16x16x32_bf16(kf1, aQ[mg][1], z, 0, 0, 0);
                    t[mg][nt] = z;
                }
            }

            // mask (diagonal region only) + exp2 + lane-local l-sum + lane-local
            // repack into PV A-frags (key order psi: j<4 -> tile 2h, j>=4 -> 2h+1)
            bv8 aP[2][2];
            for (int mg = 0; mg < 2; mg++) {
                const int qrow = qrow_base + mg * 16;
                if (kt >= 2 * qt) {
                    for (int nt = 0; nt < 4; nt++) {
                        int keyb = kt * 64 + nt * 16 + lq * 4;
                        for (int r = 0; r < 4; r++)
                            t[mg][nt][r] = (keyb + r <= qrow) ? t[mg][nt][r] : -1e30f;
                    }
                }
                for (int nt = 0; nt < 4; nt++)
                    for (int r = 0; r < 4; r++) {
                        float p = __builtin_amdgcn_exp2f(t[mg][nt][r]);
                        rsum[mg] += p;
                        t[mg][nt][r] = p;
                    }
                for (int h = 0; h < 2; h++) {
                    union { unsigned u[4]; bv8 v; } pk;
                    pk.u[0] = pk2(t[mg][2 * h][0],     t[mg][2 * h][1]);
                    pk.u[1] = pk2(t[mg][2 * h][2],     t[mg][2 * h][3]);
                    pk.u[2] = pk2(t[mg][2 * h + 1][0], t[mg][2 * h + 1][1]);
                    pk.u[3] = pk2(t[mg][2 * h + 1][2], t[mg][2 * h + 1][3]);
                    aP[mg][h] = pk.v;
                }
            }

            // O += P V with the psi key order: B-frag element j on lane (lq,lm) =
            // V[32h + (j>>2)*16 + lq*4 + (j&3)][d = nt*16+lm] -> two 8B reads.
            for (int nt = 0; nt < 4; nt++) {
                const short* vrow = &Vs[b][(nt * 16 + lm) * 64];
                for (int h = 0; h < 2; h++) {
                    int c8 = h * 4 + (lq >> 1);
                    union { sv4 q[2]; bv8 v; } vv;
                    vv.q[0] = *(const sv4*)(vrow + ((c8 ^ sw) * 8)       + (lq & 1) * 4);
                    vv.q[1] = *(const sv4*)(vrow + (((c8 ^ 2) ^ sw) * 8) + (lq & 1) * 4);
                    for (int mg = 0; mg < 2; mg++)
                        oacc[mg][nt] = __builtin_amdgcn_mfma_f32_16x16x32_bf16(aP[mg][h], vv.v, oacc[mg][nt], 0, 0, 0);
                }
            }
            __syncthreads();   // releases buf b for the next prefetch
        }

        // l-sum: add the 4 lq quadrants (each lane then has full sum for query lm)
        for (int mg = 0; mg < 2; mg++) {
            rsum[mg] += __shfl_xor(rsum[mg], 16, 64);
            rsum[mg] += __shfl_xor(rsum[mg], 32, 64);
        }

        // epilogue: oacc rows are queries lq*4+r; fetch that query's l from lane lq*4+r
        for (int mg = 0; mg < 2; mg++)
            for (int r = 0; r < 4; r++) {
                float l = __shfl(rsum[mg], lq * 4 + r, 64);
                float inv = 1.0f / l;
                int srow = q0 + wave * 32 + mg * 16 + lq * 4 + r;
                size_t rowbase = ((size_t)(bb * SEQ + srow)) * DM + hh * DK;
                for (int nt = 0; nt < 4; nt++)
                    Cb[rowbase + nt * 16 + lm] = f2b(oacc[mg][nt][r] * inv);
            }
    }
}

// ---------------------------------------------------------------------------
extern "C" void kernel_launch(void* const* d_in, const int* in_sizes, int n_in,
                              void* d_out, int out_size, void* d_ws, size_t ws_size,
                              hipStream_t stream)
{
    const float* x  = (const float*)d_in[0];
    const float* Wq = (const float*)d_in[1];
    const float* Wk = (const float*)d_in[2];
    const float* Wv = (const float*)d_in[3];
    const float* Wo = (const float*)d_in[4];
    float* out = (float*)d_out;

    const size_t TSZ = (size_t)BH * SEQ * DK;   // 8,388,608 elems (16 MB bf16)
    short* Qb  = (short*)d_ws;
    short* Kb  = Qb + TSZ;
    short* Vb  = Kb + TSZ;
    short* XCb = Vb + TSZ;            // x-bf16 during proj; ctx after attention
    short* Wb  = XCb + TSZ;           // 4x [1024][1024] bf16 (Wq,Wk,Wv,Wo)

    // fp32 -> bf16 pre-convert (x + all four W), exact 6144-block grid
    cvt_kernel<<<dim3(6144), 256, 0, stream>>>(x, Wq, Wk, Wv, Wo, XCb, Wb);
    // QKV projection + fused RoPE (z: 0=Q scaled,1=K,2=V transposed)
    gemm_nt<false><<<dim3(8, 64, 3), 256, 0, stream>>>(
        XCb, Wb, Qb, Kb, Vb, nullptr);
    // causal flash attention -> ctx (aliases XCb)
    attn_kernel<<<dim3(SEQ / 256, BH), 256, 0, stream>>>(Qb, Kb, Vb, XCb);
    // output projection (fp32 out)
    gemm_nt<true><<<dim3(8, 64, 1), 256, 0, stream>>>(
        XCb, Wb + 3 * (size_t)(DM * DM), nullptr, nullptr, nullptr, out);
}